// Round 1
// baseline (7136.623 us; speedup 1.0000x reference)
//
#include <hip/hip_runtime.h>
#include <hip/hip_cooperative_groups.h>
#include <math.h>

namespace cg = cooperative_groups;

#define GRID 512
#define BLOCK 256
#define NTH (GRID*BLOCK)
#define NWV (NTH/64)
#define INTMAX_ 0x7fffffff

struct KParams {
  const float* x;
  const int*   ei;
  const float* w;
  const float* bb;
  float* out;
  int n, e, d, out_size;
  int* ws;
  long long ws_ints;
};

__global__ __launch_bounds__(BLOCK, 2) void kmis_all(KParams P) {
  cg::grid_group grid = cg::this_grid();
  const int tid = threadIdx.x;
  const int bid = blockIdx.x;
  const int gid = bid*BLOCK + tid;
  const int lane = tid & 63;
  const int wib = tid >> 6;
  const int gw  = gid >> 6;
  const int n = P.n, e = P.e, d = P.d;
  const int d4 = d >> 2;
  const int* row = P.ei;
  const int* col = P.ei + e;

  int* ws = P.ws;
  float*    score = (float*)ws;                    // n
  int*      ks1   = ws + (size_t)1*n;
  int*      ks2   = ws + (size_t)2*n;
  unsigned* keyA  = (unsigned*)(ws + (size_t)3*n);
  unsigned* idxA  = (unsigned*)(ws + (size_t)4*n);
  unsigned* keyB  = (unsigned*)(ws + (size_t)5*n);
  unsigned* idxB  = (unsigned*)(ws + (size_t)6*n);
  unsigned* lrank = (unsigned*)(ws + (size_t)7*n);
  int*      rank  = ws + (size_t)8*n;
  int*      mr    = ws + (size_t)9*n;
  int*      tmp   = ws + (size_t)10*n;
  int*      mis   = ws + (size_t)11*n;
  int*      mm    = ws + (size_t)12*n;
  int*      misPre= ws + (size_t)13*n;
  int*      r2c   = ws + (size_t)14*n;
  int*      clus  = ws + (size_t)15*n;
  unsigned* bh    = (unsigned*)(ws + (size_t)16*n); // 256*GRID
  unsigned* dtot  = bh + 256*GRID;                  // 256
  unsigned* dbase = dtot + 256;                     // 256
  unsigned* btot  = dbase + 256;                    // GRID
  unsigned* bbase = btot + GRID;                    // GRID
  int*      cnts  = (int*)(bbase + GRID);           // 16
  int*      pairCnt = cnts + 16;
  const long long fixedInts = 16ll*n + 256ll*GRID + 256 + 256 + GRID + GRID + 16;

  __shared__ int ldsH[1024];
  __shared__ int ldsS[256];

  // ---------- Phase A: score = sigmoid(x@w + b) (f64 accum), init ks1/cnts
  {
    double bconst = (double)P.bb[0];
    const float4* w4 = (const float4*)P.w;
    for (int v = gw; v < n; v += NWV) {
      const float4* xr = (const float4*)(P.x + (size_t)v*d);
      double s = 0.0;
      for (int q = lane; q < d4; q += 64) {
        float4 xv = xr[q];
        float4 wv = w4[q];
        s += (double)xv.x*(double)wv.x + (double)xv.y*(double)wv.y
           + (double)xv.z*(double)wv.z + (double)xv.w*(double)wv.w;
      }
      for (int off = 32; off > 0; off >>= 1) s += __shfl_down(s, off);
      if (lane == 0) {
        double z = s + bconst;
        score[v] = (float)(1.0/(1.0+exp(-z)));
      }
    }
    for (int v = gid; v < n; v += NTH) ks1[v] = 0;
    if (gid == 0) { cnts[0] = 0; cnts[1] = 0; }
  }
  grid.sync();
  // ---------- ks: 2 rounds of segment_sum (exact int arithmetic)
  for (int j = gid; j < e; j += NTH) atomicAdd(&ks1[col[j]], 1);
  grid.sync();
  for (int v = gid; v < n; v += NTH) { int k = ks1[v] + 1; ks1[v] = k; ks2[v] = k; }
  grid.sync();
  for (int j = gid; j < e; j += NTH) atomicAdd(&ks2[col[j]], ks1[row[j]]);
  grid.sync();
  // ---------- keygen: descending-sortable transform of upd = s/ks
  for (int v = gid; v < n; v += NTH) {
    float upd = score[v] / (float)ks2[v];
    unsigned u = __float_as_uint(upd);
    u = (u & 0x80000000u) ? (~u) : (u | 0x80000000u);  // ascending order map
    keyA[v] = ~u;                                      // descending
    idxA[v] = (unsigned)v;
  }
  grid.sync();
  // ---------- stable LSD radix sort (4 x 8-bit), payload = node index
  {
    const int chunk = (n + GRID - 1) / GRID;
    unsigned *sk = keyA, *si = idxA, *dk = keyB, *di = idxB;
    for (int pass = 0; pass < 4; ++pass) {
      const int shift = pass * 8;
      for (int i = tid; i < 1024; i += BLOCK) ldsH[i] = 0;
      __syncthreads();
      const int ig = bid*chunk + tid;
      const bool valid = (tid < chunk) && (ig < n);
      unsigned key = 0; int dig = 0;
      if (valid) { key = sk[ig]; dig = (int)((key >> shift) & 255u); }
      unsigned long long mmask = __ballot(valid);
      for (int b2 = 0; b2 < 8; ++b2) {
        unsigned long long bm = __ballot((dig >> b2) & 1);
        mmask &= ((dig >> b2) & 1) ? bm : ~bm;
      }
      int lp = 0;
      if (valid) {
        lp = __popcll(mmask & ((1ull << lane) - 1ull));
        if (lp == 0) ldsH[wib*256 + dig] = __popcll(mmask);  // group leader
      }
      __syncthreads();
      if (tid < 256) {
        int c0 = ldsH[tid], c1 = ldsH[256+tid], c2 = ldsH[512+tid], c3 = ldsH[768+tid];
        ldsH[tid] = 0; ldsH[256+tid] = c0; ldsH[512+tid] = c0+c1; ldsH[768+tid] = c0+c1+c2;
        bh[(size_t)tid*GRID + bid] = (unsigned)(c0+c1+c2+c3);
      }
      __syncthreads();
      if (valid) lrank[ig] = (unsigned)(ldsH[wib*256 + dig] + lp);
      grid.sync();
      if (gw < 256) {            // per-digit exclusive scan across blocks
        const int dg = gw;
        unsigned running = 0;
        for (int r = 0; r < GRID/64; ++r) {
          unsigned v = bh[(size_t)dg*GRID + r*64 + lane];
          unsigned incl = v;
          for (int off = 1; off < 64; off <<= 1) { unsigned t = __shfl_up(incl, off); if (lane >= off) incl += t; }
          bh[(size_t)dg*GRID + r*64 + lane] = incl - v + running;
          running += __shfl(incl, 63);
        }
        if (lane == 0) dtot[dg] = running;
      }
      grid.sync();
      if (gw == 0) {             // exclusive scan of 256 digit totals
        unsigned running = 0;
        for (int r = 0; r < 4; ++r) {
          unsigned v = dtot[r*64 + lane];
          unsigned incl = v;
          for (int off = 1; off < 64; off <<= 1) { unsigned t = __shfl_up(incl, off); if (lane >= off) incl += t; }
          dbase[r*64 + lane] = incl - v + running;
          running += __shfl(incl, 63);
        }
      }
      grid.sync();
      if (valid) {
        unsigned pos = dbase[dig] + bh[(size_t)dig*GRID + bid] + lrank[ig];
        dk[pos] = key; di[pos] = si[ig];
      }
      grid.sync();
      unsigned* t;
      t = sk; sk = dk; dk = t;
      t = si; si = di; di = t;
    }
  } // sorted (key asc = upd desc, ties by idx) now in keyA/idxA
  // ---------- rank + loop init
  for (int i = gid; i < n; i += NTH) { int v = (int)idxA[i]; rank[v] = i; mr[v] = i; }
  for (int v = gid; v < n; v += NTH) { mis[v] = 0; tmp[v] = INTMAX_; }
  grid.sync();
  // ---------- KMIS while-loop
  int iter = 0;
  for (;;) {
    if (gid == 0) cnts[iter & 1] = 0;
    for (int j = gid; j < e; j += NTH) atomicMin(&tmp[col[j]], mr[row[j]]);
    grid.sync();
    for (int v = gid; v < n; v += NTH) { int t = tmp[v]; if (t < mr[v]) mr[v] = t; tmp[v] = INTMAX_; }
    grid.sync();
    for (int j = gid; j < e; j += NTH) atomicMin(&tmp[col[j]], mr[row[j]]);
    grid.sync();
    for (int v = gid; v < n; v += NTH) {
      int m2 = mr[v]; int t = tmp[v]; if (t < m2) m2 = t;
      mr[v] = m2;
      int ms = mis[v] | ((rank[v] == m2) ? 1 : 0);
      mis[v] = ms; mm[v] = ms; tmp[v] = 0;
    }
    grid.sync();
    for (int j = gid; j < e; j += NTH) atomicMax(&tmp[col[j]], mm[row[j]]);
    grid.sync();
    for (int v = gid; v < n; v += NTH) { int t = tmp[v]; if (t > mm[v]) mm[v] = t; tmp[v] = 0; }
    grid.sync();
    for (int j = gid; j < e; j += NTH) atomicMax(&tmp[col[j]], mm[row[j]]);
    grid.sync();
    int localUn = 0;
    for (int v = gid; v < n; v += NTH) {
      int mk = mm[v] | tmp[v];
      tmp[v] = INTMAX_;
      if (mk) { mr[v] = n; } else { mr[v] = rank[v]; ++localUn; }
    }
    ldsS[tid] = localUn; __syncthreads();
    for (int off = 128; off > 0; off >>= 1) { if (tid < off) ldsS[tid] += ldsS[tid+off]; __syncthreads(); }
    if (tid == 0 && ldsS[0]) atomicAdd(&cnts[iter & 1], ldsS[0]);
    grid.sync();
    int un = __hip_atomic_load(&cnts[iter & 1], __ATOMIC_RELAXED, __HIP_MEMORY_SCOPE_AGENT);
    if (un == 0 || iter >= 1000) break;
    ++iter;
  }
  // ---------- final khop_min over (mis ? rank : n)
  for (int v = gid; v < n; v += NTH) mr[v] = mis[v] ? rank[v] : n;
  grid.sync();
  for (int j = gid; j < e; j += NTH) atomicMin(&tmp[col[j]], mr[row[j]]);
  grid.sync();
  for (int v = gid; v < n; v += NTH) { int t = tmp[v]; if (t < mr[v]) mr[v] = t; tmp[v] = INTMAX_; }
  grid.sync();
  for (int j = gid; j < e; j += NTH) atomicMin(&tmp[col[j]], mr[row[j]]);
  grid.sync();
  // combine + mis prefix-scan (contiguous block chunks)
  {
    for (int v = gid; v < n; v += NTH) { int t = tmp[v]; if (t < mr[v]) mr[v] = t; }
    const int chunk = (n + GRID - 1) / GRID;
    const int ig = bid*chunk + tid;
    const bool valid = (tid < chunk) && (ig < n);
    int v2 = valid ? mis[ig] : 0;
    ldsS[tid] = v2; __syncthreads();
    for (int off = 1; off < 256; off <<= 1) {
      int t = (tid >= off) ? ldsS[tid-off] : 0; __syncthreads();
      ldsS[tid] += t; __syncthreads();
    }
    int incl = ldsS[tid];
    int total = ldsS[255];
    if (valid) misPre[ig] = incl - v2;
    if (tid == 0) btot[bid] = (unsigned)total;
  }
  grid.sync();
  if (gw == 0) {
    unsigned running = 0;
    for (int r = 0; r < GRID/64; ++r) {
      unsigned v = btot[r*64 + lane];
      unsigned incl = v;
      for (int off = 1; off < 64; off <<= 1) { unsigned t = __shfl_up(incl, off); if (lane >= off) incl += t; }
      bbase[r*64 + lane] = incl - v + running;
      running += __shfl(incl, 63);
    }
    if (lane == 0) cnts[2] = (int)running;   // num_mis
  }
  grid.sync();
  {
    const int chunk = (n + GRID - 1) / GRID;
    const int ig = bid*chunk + tid;
    if (tid < chunk && ig < n) {
      int p = misPre[ig] + (int)bbase[bid];
      misPre[ig] = p;
      if (mis[ig]) r2c[rank[ig]] = p;       // rank -> cluster index
    }
  }
  grid.sync();
  const int M = __hip_atomic_load(&cnts[2], __ATOMIC_RELAXED, __HIP_MEMORY_SCOPE_AGENT);
  const long long M2ll = (long long)M * (long long)M;
  const bool pairOk = (M > 0) && (M2ll < 0x7fffffffll) && (fixedInts + M2ll <= P.ws_ints);
  // cluster + zero pair counts
  for (int v = gid; v < n; v += NTH) {
    int r3 = mr[v];
    clus[v] = (r3 >= 0 && r3 < n) ? r2c[r3] : 0;
  }
  if (pairOk) {
    const int m2i = (int)M2ll;
    for (int i = gid; i < m2i; i += NTH) pairCnt[i] = 0;
  }
  grid.sync();
  if (pairOk) {
    for (int j = gid; j < e; j += NTH) {
      int a = clus[row[j]], b2 = clus[col[j]];
      atomicAdd(&pairCnt[a*M + b2], 1);
    }
  }
  grid.sync();
  // compact: count kept (cnt>0 && a!=b) per block
  const int m2i = pairOk ? (int)M2ll : 0;
  const int chunkP = pairOk ? (int)((M2ll + GRID - 1) / GRID) : 0;
  int pstart = bid * chunkP; if (pstart > m2i) pstart = m2i;
  int pend = pstart + chunkP; if (pend > m2i) pend = m2i;
  {
    int localKeep = 0;
    for (int i = pstart + tid; i < pend; i += BLOCK) {
      int c = pairCnt[i];
      if (c > 0 && (i / M) != (i % M)) ++localKeep;
    }
    ldsS[tid] = localKeep; __syncthreads();
    for (int off = 128; off > 0; off >>= 1) { if (tid < off) ldsS[tid] += ldsS[tid+off]; __syncthreads(); }
    if (tid == 0) btot[bid] = (unsigned)ldsS[0];
  }
  grid.sync();
  if (gw == 0) {
    unsigned running = 0;
    for (int r = 0; r < GRID/64; ++r) {
      unsigned v = btot[r*64 + lane];
      unsigned incl = v;
      for (int off = 1; off < 64; off <<= 1) { unsigned t = __shfl_up(incl, off); if (lane >= off) incl += t; }
      bbase[r*64 + lane] = incl - v + running;
      running += __shfl(incl, 63);
    }
    if (lane == 0) cnts[3] = (int)running;   // E_keep
  }
  grid.sync();
  const int EK = __hip_atomic_load(&cnts[3], __ATOMIC_RELAXED, __HIP_MEMORY_SCOPE_AGENT);
  const size_t eBase = (size_t)M * (size_t)d;
  const bool outOk = pairOk && (eBase + 3ull*(size_t)EK <= (size_t)P.out_size);
  // ordered edge writes (ascending pair key == jnp.unique lexicographic order)
  if (m2i > 0) {
    int running2 = (int)bbase[bid];
    for (int t0 = pstart; t0 < pend; t0 += BLOCK) {
      int i = t0 + tid;
      int c = 0, kept = 0, a = 0, b2 = 0;
      if (i < pend) {
        c = pairCnt[i];
        a = i / M; b2 = i % M;
        kept = (c > 0 && a != b2) ? 1 : 0;
      }
      ldsS[tid] = kept; __syncthreads();
      for (int off = 1; off < 256; off <<= 1) {
        int t = (tid >= off) ? ldsS[tid-off] : 0; __syncthreads();
        ldsS[tid] += t; __syncthreads();
      }
      int incl = ldsS[tid]; int tot = ldsS[255];
      if (kept && outOk) {
        int j2 = running2 + incl - 1;
        P.out[eBase + (size_t)j2] = (float)a;
        P.out[eBase + (size_t)EK + (size_t)j2] = (float)b2;
        P.out[eBase + 2ull*(size_t)EK + (size_t)j2] = (float)c;
      }
      running2 += tot;
      __syncthreads();
    }
  }
  // x_pool = (x * score)[mis_idx]
  if (eBase <= (size_t)P.out_size) {
    for (int v = gw; v < n; v += NWV) {
      if (mis[v]) {
        int p = misPre[v];
        float sc = score[v];
        const float4* xr = (const float4*)(P.x + (size_t)v*d);
        float4* outr = (float4*)P.out + (size_t)p*d4;
        for (int q = lane; q < d4; q += 64) {
          float4 xv = xr[q];
          float4 o; o.x = xv.x*sc; o.y = xv.y*sc; o.z = xv.z*sc; o.w = xv.w*sc;
          outr[q] = o;
        }
      }
    }
  }
}

extern "C" void kernel_launch(void* const* d_in, const int* in_sizes, int n_in,
                              void* d_out, int out_size, void* d_ws, size_t ws_size,
                              hipStream_t stream) {
  KParams P;
  P.x  = (const float*)d_in[0];
  P.ei = (const int*)d_in[1];
  P.w  = (const float*)d_in[2];
  P.bb = (const float*)d_in[3];
  P.out = (float*)d_out;
  P.d = in_sizes[2];            // 256
  P.n = in_sizes[0] / P.d;      // 100000
  P.e = in_sizes[1] / 2;        // 1600000
  P.out_size = out_size;
  P.ws = (int*)d_ws;
  P.ws_ints = (long long)(ws_size / 4);
  void* args[] = { &P };
  hipLaunchCooperativeKernel((const void*)kmis_all, dim3(GRID), dim3(BLOCK), args, 0, stream);
}

// Round 2
// 4351.241 us; speedup vs baseline: 1.6401x; 1.6401x over previous
//
#include <hip/hip_runtime.h>
#include <hip/hip_cooperative_groups.h>
#include <math.h>

namespace cg = cooperative_groups;

#define GRID 512
#define BLOCK 256
#define NTH (GRID*BLOCK)
#define NWV (NTH/64)

struct KParams {
  const float* x;
  const int*   ei;
  const float* w;
  const float* bb;
  float* out;
  int n, e, d, out_size;
  int* ws;
  long long ws_ints;
};

__global__ __launch_bounds__(BLOCK, 2) void kmis_all(KParams P) {
  cg::grid_group grid = cg::this_grid();
  const int tid = threadIdx.x;
  const int bid = blockIdx.x;
  const int gid = bid*BLOCK + tid;
  const int lane = tid & 63;
  const int wib = tid >> 6;
  const int gw  = gid >> 6;
  const int n = P.n, e = P.e, d = P.d;
  const int d4 = d >> 2;
  const int* row = P.ei;
  const int* col = P.ei + e;
  const int chunk = (n + GRID - 1) / GRID;

  int* ws = P.ws;
  float*    score = (float*)ws;                    // n
  int*      ks1   = ws + (size_t)1*n;              // in-degree, then deg+1
  int*      cursor= ws + (size_t)2*n;
  unsigned* keyA  = (unsigned*)(ws + (size_t)3*n);
  unsigned* idxA  = (unsigned*)(ws + (size_t)4*n);
  unsigned* keyB  = (unsigned*)(ws + (size_t)5*n);
  unsigned* idxB  = (unsigned*)(ws + (size_t)6*n);
  unsigned* lrank = (unsigned*)(ws + (size_t)7*n);
  int*      rank  = ws + (size_t)8*n;
  int*      mr    = ws + (size_t)9*n;
  int*      t1    = ws + (size_t)10*n;
  int*      mis   = ws + (size_t)11*n;
  int*      mm    = ws + (size_t)12*n;
  int*      misPre= ws + (size_t)13*n;
  int*      r2c   = ws + (size_t)14*n;
  int*      clus  = ws + (size_t)15*n;
  int*      colPtr= ws + (size_t)16*n;             // n+1
  int*      small_ = ws + (size_t)17*n + 64;
  unsigned* bh    = (unsigned*)small_;             // 256*GRID
  unsigned* dtot  = bh + 256*GRID;                 // 256
  unsigned* dbase = dtot + 256;                    // 256
  unsigned* btot  = dbase + 256;                   // GRID
  unsigned* bbase = btot + GRID;                   // GRID
  int*      cnts  = (int*)(bbase + GRID);          // 16
  const long long unionBase = 17ll*n + 64 + 256ll*GRID + 512 + 2ll*GRID + 16;
  int*      colSrc  = ws + unionBase;              // e ints (phase 1)
  int*      pairCnt = ws + unionBase;              // M*M ints (phase 2, aliased)

  __shared__ int ldsH[1024];
  __shared__ int ldsS[256];

  // ---------- Phase A: score = sigmoid(x@w + b) (f64 accum); zero ks1
  {
    double bconst = (double)P.bb[0];
    const float4* w4 = (const float4*)P.w;
    for (int v = gw; v < n; v += NWV) {
      const float4* xr = (const float4*)(P.x + (size_t)v*d);
      double s = 0.0;
      for (int q = lane; q < d4; q += 64) {
        float4 xv = xr[q];
        float4 wv = w4[q];
        s += (double)xv.x*(double)wv.x + (double)xv.y*(double)wv.y
           + (double)xv.z*(double)wv.z + (double)xv.w*(double)wv.w;
      }
      for (int off = 32; off > 0; off >>= 1) s += __shfl_down(s, off);
      if (lane == 0) {
        double z = s + bconst;
        score[v] = (float)(1.0/(1.0+exp(-z)));
      }
    }
    for (int v = gid; v < n; v += NTH) ks1[v] = 0;
  }
  grid.sync();
  // ---------- in-degree count (one-time atomic pass)
  for (int j = gid; j < e; j += NTH) atomicAdd(&ks1[col[j]], 1);
  grid.sync();
  // ---------- colPtr = exclusive scan of in-degree (block-chunked)
  {
    const int ig = bid*chunk + tid;
    const bool valid = (tid < chunk) && (ig < n);
    int v2 = valid ? ks1[ig] : 0;
    ldsS[tid] = v2; __syncthreads();
    for (int off = 1; off < 256; off <<= 1) {
      int t = (tid >= off) ? ldsS[tid-off] : 0; __syncthreads();
      ldsS[tid] += t; __syncthreads();
    }
    if (valid) colPtr[ig] = ldsS[tid] - v2;
    if (tid == 0) btot[bid] = (unsigned)ldsS[255];
  }
  grid.sync();
  if (gw == 0) {
    unsigned running = 0;
    for (int r = 0; r < GRID/64; ++r) {
      unsigned v = btot[r*64 + lane];
      unsigned incl = v;
      for (int off = 1; off < 64; off <<= 1) { unsigned t = __shfl_up(incl, off); if (lane >= off) incl += t; }
      bbase[r*64 + lane] = incl - v + running;
      running += __shfl(incl, 63);
    }
  }
  grid.sync();
  {
    const int ig = bid*chunk + tid;
    if (tid < chunk && ig < n) {
      int cp = colPtr[ig] + (int)bbase[bid];
      colPtr[ig] = cp;
      cursor[ig] = cp;
      ks1[ig] = ks1[ig] + 1;     // ks after round 1 = indeg + 1
    }
    if (gid == 0) colPtr[n] = e;
  }
  grid.sync();
  // ---------- CSR scatter (one-time atomic pass): in-edges of col, store row
  for (int j = gid; j < e; j += NTH) {
    int pos = atomicAdd(&cursor[col[j]], 1);
    colSrc[pos] = row[j];
  }
  grid.sync();
  // ---------- ks round 2 (gather) fused with sort keygen
  for (int v = gid; v < n; v += NTH) {
    int pe_ = colPtr[v+1];
    int s = ks1[v];
    for (int p = colPtr[v]; p < pe_; ++p) s += ks1[colSrc[p]];
    float upd = score[v] / (float)s;
    unsigned u = __float_as_uint(upd);
    u = (u & 0x80000000u) ? (~u) : (u | 0x80000000u);  // ascending map
    keyA[v] = ~u;                                      // descending
    idxA[v] = (unsigned)v;
  }
  grid.sync();
  // ---------- stable LSD radix sort (4 x 8-bit), payload = node index
  {
    unsigned *sk = keyA, *si = idxA, *dk = keyB, *di = idxB;
    for (int pass = 0; pass < 4; ++pass) {
      const int shift = pass * 8;
      for (int i = tid; i < 1024; i += BLOCK) ldsH[i] = 0;
      __syncthreads();
      const int ig = bid*chunk + tid;
      const bool valid = (tid < chunk) && (ig < n);
      unsigned key = 0; int dig = 0;
      if (valid) { key = sk[ig]; dig = (int)((key >> shift) & 255u); }
      unsigned long long mmask = __ballot(valid);
      for (int b2 = 0; b2 < 8; ++b2) {
        unsigned long long bm = __ballot((dig >> b2) & 1);
        mmask &= ((dig >> b2) & 1) ? bm : ~bm;
      }
      int lp = 0;
      if (valid) {
        lp = __popcll(mmask & ((1ull << lane) - 1ull));
        if (lp == 0) ldsH[wib*256 + dig] = __popcll(mmask);
      }
      __syncthreads();
      if (tid < 256) {
        int c0 = ldsH[tid], c1 = ldsH[256+tid], c2 = ldsH[512+tid], c3 = ldsH[768+tid];
        ldsH[tid] = 0; ldsH[256+tid] = c0; ldsH[512+tid] = c0+c1; ldsH[768+tid] = c0+c1+c2;
        bh[(size_t)tid*GRID + bid] = (unsigned)(c0+c1+c2+c3);
      }
      __syncthreads();
      if (valid) lrank[ig] = (unsigned)(ldsH[wib*256 + dig] + lp);
      grid.sync();
      if (gw < 256) {
        const int dg = gw;
        unsigned running = 0;
        for (int r = 0; r < GRID/64; ++r) {
          unsigned v = bh[(size_t)dg*GRID + r*64 + lane];
          unsigned incl = v;
          for (int off = 1; off < 64; off <<= 1) { unsigned t = __shfl_up(incl, off); if (lane >= off) incl += t; }
          bh[(size_t)dg*GRID + r*64 + lane] = incl - v + running;
          running += __shfl(incl, 63);
        }
        if (lane == 0) dtot[dg] = running;
      }
      grid.sync();
      if (gw == 0) {
        unsigned running = 0;
        for (int r = 0; r < 4; ++r) {
          unsigned v = dtot[r*64 + lane];
          unsigned incl = v;
          for (int off = 1; off < 64; off <<= 1) { unsigned t = __shfl_up(incl, off); if (lane >= off) incl += t; }
          dbase[r*64 + lane] = incl - v + running;
          running += __shfl(incl, 63);
        }
      }
      grid.sync();
      if (valid) {
        unsigned pos = dbase[dig] + bh[(size_t)dig*GRID + bid] + lrank[ig];
        dk[pos] = key; di[pos] = si[ig];
      }
      grid.sync();
      unsigned* t;
      t = sk; sk = dk; dk = t;
      t = si; si = di; di = t;
    }
  } // sorted (upd desc, ties by idx) in keyA/idxA
  // ---------- rank + loop init
  for (int i = gid; i < n; i += NTH) {
    int v = (int)idxA[i];
    rank[v] = i; mr[v] = i; mis[v] = 0;
  }
  grid.sync();
  // ---------- KMIS while-loop (pure gather passes)
  int iter = 0;
  for (;;) {
    // hop-1 min
    for (int v = gid; v < n; v += NTH) {
      int pe_ = colPtr[v+1];
      int m = mr[v];
      for (int p = colPtr[v]; p < pe_; ++p) { int t = mr[colSrc[p]]; if (t < m) m = t; }
      t1[v] = m;
    }
    grid.sync();
    // hop-2 min + mis update
    for (int v = gid; v < n; v += NTH) {
      int pe_ = colPtr[v+1];
      int m = t1[v];
      for (int p = colPtr[v]; p < pe_; ++p) { int t = t1[colSrc[p]]; if (t < m) m = t; }
      mr[v] = m;
      int ms = mis[v] | ((rank[v] == m) ? 1 : 0);
      mis[v] = ms; mm[v] = ms;
    }
    if (gid == 0) cnts[iter & 1] = 0;
    grid.sync();
    // hop-1 max (0/1 values)
    for (int v = gid; v < n; v += NTH) {
      int pe_ = colPtr[v+1];
      int m = mm[v];
      for (int p = colPtr[v]; p < pe_; ++p) m |= t1[0]*0 | mm[colSrc[p]];
      t1[v] = m;
    }
    grid.sync();
    // hop-2 max + mask/reset + convergence count
    int localUn = 0;
    for (int v = gid; v < n; v += NTH) {
      int pe_ = colPtr[v+1];
      int m = t1[v];
      for (int p = colPtr[v]; p < pe_; ++p) m |= t1[colSrc[p]];
      if (m) { mr[v] = n; } else { mr[v] = rank[v]; ++localUn; }
    }
    ldsS[tid] = localUn; __syncthreads();
    for (int off = 128; off > 0; off >>= 1) { if (tid < off) ldsS[tid] += ldsS[tid+off]; __syncthreads(); }
    if (tid == 0 && ldsS[0]) atomicAdd(&cnts[iter & 1], ldsS[0]);
    grid.sync();
    int un = __hip_atomic_load(&cnts[iter & 1], __ATOMIC_RELAXED, __HIP_MEMORY_SCOPE_AGENT);
    if (un == 0 || iter >= 500) break;
    ++iter;
  }
  // ---------- final khop_min over (mis ? rank : n)
  for (int v = gid; v < n; v += NTH) mm[v] = mis[v] ? rank[v] : n;
  grid.sync();
  for (int v = gid; v < n; v += NTH) {
    int pe_ = colPtr[v+1];
    int m = mm[v];
    for (int p = colPtr[v]; p < pe_; ++p) { int t = mm[colSrc[p]]; if (t < m) m = t; }
    t1[v] = m;
  }
  grid.sync();
  for (int v = gid; v < n; v += NTH) {
    int pe_ = colPtr[v+1];
    int m = t1[v];
    for (int p = colPtr[v]; p < pe_; ++p) { int t = t1[colSrc[p]]; if (t < m) m = t; }
    mr[v] = m;
  }
  grid.sync();
  // ---------- mis prefix-scan (contiguous block chunks)
  {
    const int ig = bid*chunk + tid;
    const bool valid = (tid < chunk) && (ig < n);
    int v2 = valid ? mis[ig] : 0;
    ldsS[tid] = v2; __syncthreads();
    for (int off = 1; off < 256; off <<= 1) {
      int t = (tid >= off) ? ldsS[tid-off] : 0; __syncthreads();
      ldsS[tid] += t; __syncthreads();
    }
    if (valid) misPre[ig] = ldsS[tid] - v2;
    if (tid == 0) btot[bid] = (unsigned)ldsS[255];
  }
  grid.sync();
  if (gw == 0) {
    unsigned running = 0;
    for (int r = 0; r < GRID/64; ++r) {
      unsigned v = btot[r*64 + lane];
      unsigned incl = v;
      for (int off = 1; off < 64; off <<= 1) { unsigned t = __shfl_up(incl, off); if (lane >= off) incl += t; }
      bbase[r*64 + lane] = incl - v + running;
      running += __shfl(incl, 63);
    }
    if (lane == 0) cnts[2] = (int)running;   // num_mis
  }
  grid.sync();
  {
    const int ig = bid*chunk + tid;
    if (tid < chunk && ig < n) {
      int p = misPre[ig] + (int)bbase[bid];
      misPre[ig] = p;
      if (mis[ig]) r2c[rank[ig]] = p;       // rank -> cluster index
    }
  }
  grid.sync();
  const int M = __hip_atomic_load(&cnts[2], __ATOMIC_RELAXED, __HIP_MEMORY_SCOPE_AGENT);
  const long long M2ll = (long long)M * (long long)M;
  const bool pairOk = (M > 0) && (M2ll < 0x7fffffffll) && (unionBase + M2ll <= P.ws_ints);
  // cluster map + zero pair counts (colSrc dead from here; pairCnt aliases it)
  for (int v = gid; v < n; v += NTH) {
    int r3 = mr[v];
    clus[v] = (r3 >= 0 && r3 < n) ? r2c[r3] : 0;
  }
  if (pairOk) {
    const int m2i = (int)M2ll;
    for (int i = gid; i < m2i; i += NTH) pairCnt[i] = 0;
  }
  grid.sync();
  if (pairOk) {
    for (int j = gid; j < e; j += NTH) {
      int a = clus[row[j]], b2 = clus[col[j]];
      atomicAdd(&pairCnt[a*M + b2], 1);
    }
  }
  grid.sync();
  // ---------- compact kept pairs
  const int m2i = pairOk ? (int)M2ll : 0;
  const int chunkP = pairOk ? (int)((M2ll + GRID - 1) / GRID) : 0;
  int pstart = bid * chunkP; if (pstart > m2i) pstart = m2i;
  int pend = pstart + chunkP; if (pend > m2i) pend = m2i;
  {
    int localKeep = 0;
    for (int i = pstart + tid; i < pend; i += BLOCK) {
      int c = pairCnt[i];
      if (c > 0 && (i / M) != (i % M)) ++localKeep;
    }
    ldsS[tid] = localKeep; __syncthreads();
    for (int off = 128; off > 0; off >>= 1) { if (tid < off) ldsS[tid] += ldsS[tid+off]; __syncthreads(); }
    if (tid == 0) btot[bid] = (unsigned)ldsS[0];
  }
  grid.sync();
  if (gw == 0) {
    unsigned running = 0;
    for (int r = 0; r < GRID/64; ++r) {
      unsigned v = btot[r*64 + lane];
      unsigned incl = v;
      for (int off = 1; off < 64; off <<= 1) { unsigned t = __shfl_up(incl, off); if (lane >= off) incl += t; }
      bbase[r*64 + lane] = incl - v + running;
      running += __shfl(incl, 63);
    }
    if (lane == 0) cnts[3] = (int)running;   // E_keep
  }
  grid.sync();
  const int EK = __hip_atomic_load(&cnts[3], __ATOMIC_RELAXED, __HIP_MEMORY_SCOPE_AGENT);
  const size_t eBase = (size_t)M * (size_t)d;
  const bool outOk = pairOk && (eBase + 3ull*(size_t)EK <= (size_t)P.out_size);
  // ordered edge writes (ascending pair key == jnp.unique lexicographic order)
  if (m2i > 0) {
    int running2 = (int)bbase[bid];
    for (int t0 = pstart; t0 < pend; t0 += BLOCK) {
      int i = t0 + tid;
      int c = 0, kept = 0, a = 0, b2 = 0;
      if (i < pend) {
        c = pairCnt[i];
        a = i / M; b2 = i % M;
        kept = (c > 0 && a != b2) ? 1 : 0;
      }
      ldsS[tid] = kept; __syncthreads();
      for (int off = 1; off < 256; off <<= 1) {
        int t = (tid >= off) ? ldsS[tid-off] : 0; __syncthreads();
        ldsS[tid] += t; __syncthreads();
      }
      int incl = ldsS[tid]; int tot = ldsS[255];
      if (kept && outOk) {
        int j2 = running2 + incl - 1;
        P.out[eBase + (size_t)j2] = (float)a;
        P.out[eBase + (size_t)EK + (size_t)j2] = (float)b2;
        P.out[eBase + 2ull*(size_t)EK + (size_t)j2] = (float)c;
      }
      running2 += tot;
      __syncthreads();
    }
  }
  // ---------- x_pool = (x * score)[mis_idx]
  if (eBase <= (size_t)P.out_size) {
    for (int v = gw; v < n; v += NWV) {
      if (mis[v]) {
        int p = misPre[v];
        float sc = score[v];
        const float4* xr = (const float4*)(P.x + (size_t)v*d);
        float4* outr = (float4*)P.out + (size_t)p*d4;
        for (int q = lane; q < d4; q += 64) {
          float4 xv = xr[q];
          float4 o; o.x = xv.x*sc; o.y = xv.y*sc; o.z = xv.z*sc; o.w = xv.w*sc;
          outr[q] = o;
        }
      }
    }
  }
}

extern "C" void kernel_launch(void* const* d_in, const int* in_sizes, int n_in,
                              void* d_out, int out_size, void* d_ws, size_t ws_size,
                              hipStream_t stream) {
  KParams P;
  P.x  = (const float*)d_in[0];
  P.ei = (const int*)d_in[1];
  P.w  = (const float*)d_in[2];
  P.bb = (const float*)d_in[3];
  P.out = (float*)d_out;
  P.d = in_sizes[2];            // 256
  P.n = in_sizes[0] / P.d;      // 100000
  P.e = in_sizes[1] / 2;        // 1600000
  P.out_size = out_size;
  P.ws = (int*)d_ws;
  P.ws_ints = (long long)(ws_size / 4);
  void* args[] = { &P };
  hipLaunchCooperativeKernel((const void*)kmis_all, dim3(GRID), dim3(BLOCK), args, 0, stream);
}

// Round 3
// 2318.617 us; speedup vs baseline: 3.0780x; 1.8767x over previous
//
#include <hip/hip_runtime.h>
#include <hip/hip_cooperative_groups.h>
#include <math.h>

namespace cg = cooperative_groups;

#define BLOCK 256
#define EGRID 2048                 // edge-parallel / bulk kernels
#define SG    512                  // scan/sort kernels (fixed structure)
#define LGRID 400                  // cooperative while-loop (400*256 >= n)
#define NTHE (EGRID*BLOCK)
#define NWVE (NTHE/64)

struct KParams {
  const float* x;
  const int*   ei;
  const float* w;
  const float* bb;
  float* out;
  int n, e, d, out_size;
  int* ws;
  long long ws_ints;
};

struct Lay {
  float* score; int *ks1,*cursor;
  unsigned *keyA,*idxA,*keyB,*idxB,*lrank;
  int *rank,*mr,*t1,*mis,*mm,*misPre,*r2c,*clus,*colPtr;
  unsigned *bh,*dtot,*dbase,*btot,*bbase;
  int *cnts,*colSrc,*pairCnt;
  long long unionBase;
};

__device__ inline Lay mklay(int* ws, int n) {
  Lay L;
  L.score=(float*)ws;
  L.ks1   = ws + (size_t)1*n;
  L.cursor= ws + (size_t)2*n;
  L.keyA  = (unsigned*)(ws + (size_t)3*n);
  L.idxA  = (unsigned*)(ws + (size_t)4*n);
  L.keyB  = (unsigned*)(ws + (size_t)5*n);
  L.idxB  = (unsigned*)(ws + (size_t)6*n);
  L.lrank = (unsigned*)(ws + (size_t)7*n);
  L.rank  = ws + (size_t)8*n;
  L.mr    = ws + (size_t)9*n;
  L.t1    = ws + (size_t)10*n;
  L.mis   = ws + (size_t)11*n;
  L.mm    = ws + (size_t)12*n;
  L.misPre= ws + (size_t)13*n;
  L.r2c   = ws + (size_t)14*n;
  L.clus  = ws + (size_t)15*n;
  L.colPtr= ws + (size_t)16*n;          // n+1
  int* sm = ws + (size_t)17*n + 64;
  L.bh    = (unsigned*)sm;              // 256*SG
  L.dtot  = L.bh + 256*SG;              // 256
  L.dbase = L.dtot + 256;               // 256
  L.btot  = L.dbase + 256;              // SG
  L.bbase = L.btot + SG;                // SG
  L.cnts  = (int*)(L.bbase + SG);       // 16
  L.unionBase = 17ll*n + 64 + 256ll*SG + 512 + 2ll*SG + 16;
  L.colSrc  = ws + L.unionBase;         // e ints (phase 1)
  L.pairCnt = ws + L.unionBase;         // M*M ints (phase 2, aliased)
  return L;
}

// ---- unrolled gather reducers (4 independent loads in flight) ----
__device__ inline int gmin_(const int* __restrict__ s, const int* __restrict__ val,
                            int p, int pe, int m) {
  for (; p+3 < pe; p += 4) {
    int a0=s[p],a1=s[p+1],a2=s[p+2],a3=s[p+3];
    int t0=val[a0],t1=val[a1],t2=val[a2],t3=val[a3];
    t0=min(t0,t1); t2=min(t2,t3); t0=min(t0,t2); if (t0<m) m=t0;
  }
  for (; p<pe; ++p){ int t=val[s[p]]; if (t<m) m=t; }
  return m;
}
__device__ inline int gor_(const int* __restrict__ s, const int* __restrict__ val,
                           int p, int pe, int m) {
  for (; p+3 < pe; p += 4) m |= val[s[p]] | val[s[p+1]] | val[s[p+2]] | val[s[p+3]];
  for (; p<pe; ++p) m |= val[s[p]];
  return m;
}
__device__ inline int gsum_(const int* __restrict__ s, const int* __restrict__ val,
                            int p, int pe, int m) {
  for (; p+3 < pe; p += 4) m += val[s[p]] + val[s[p+1]] + val[s[p+2]] + val[s[p+3]];
  for (; p<pe; ++p) m += val[s[p]];
  return m;
}

// ---------------- phase kernels ----------------
__global__ __launch_bounds__(BLOCK) void k_score(KParams P) {
  Lay L = mklay(P.ws, P.n);
  int gid = blockIdx.x*BLOCK + threadIdx.x;
  int lane = gid & 63, gwv = gid >> 6;
  int d4 = P.d >> 2;
  double bconst = (double)P.bb[0];
  const float4* w4 = (const float4*)P.w;
  for (int v = gwv; v < P.n; v += NWVE) {
    const float4* xr = (const float4*)(P.x + (size_t)v*P.d);
    double s = 0.0;
    for (int q = lane; q < d4; q += 64) {
      float4 xv = xr[q], wv = w4[q];
      s += (double)xv.x*wv.x + (double)xv.y*wv.y + (double)xv.z*wv.z + (double)xv.w*wv.w;
    }
    for (int off = 32; off > 0; off >>= 1) s += __shfl_down(s, off);
    if (lane == 0) L.score[v] = (float)(1.0/(1.0+exp(-(s+bconst))));
  }
  for (int v = gid; v < P.n; v += NTHE) L.ks1[v] = 0;
}

__global__ __launch_bounds__(BLOCK) void k_degree(KParams P) {
  Lay L = mklay(P.ws, P.n);
  const int* col = P.ei + P.e;
  int gid = blockIdx.x*BLOCK + threadIdx.x;
  for (int j = gid; j < P.e; j += NTHE) atomicAdd(&L.ks1[col[j]], 1);
}

__global__ __launch_bounds__(BLOCK) void k_scan1(KParams P) {
  Lay L = mklay(P.ws, P.n);
  __shared__ int lds[256];
  int tid = threadIdx.x, bid = blockIdx.x;
  int chunk = (P.n + SG - 1)/SG;
  int ig = bid*chunk + tid;
  bool valid = (tid < chunk) && (ig < P.n);
  int v2 = valid ? L.ks1[ig] : 0;
  lds[tid] = v2; __syncthreads();
  for (int off = 1; off < 256; off <<= 1) {
    int t = (tid >= off) ? lds[tid-off] : 0; __syncthreads();
    lds[tid] += t; __syncthreads();
  }
  if (valid) L.colPtr[ig] = lds[tid] - v2;
  if (tid == 0) L.btot[bid] = (unsigned)lds[255];
}

// 1-block, 64-thread: scan btot[0..cnt) -> bbase; total -> cnts[slot] if slot>=0
__global__ void k_scanB(KParams P, int cnt, int slot) {
  Lay L = mklay(P.ws, P.n);
  int lane = threadIdx.x;
  unsigned running = 0;
  for (int r = 0; r*64 < cnt; ++r) {
    int idx = r*64 + lane;
    unsigned v = (idx < cnt) ? L.btot[idx] : 0u;
    unsigned incl = v;
    for (int off = 1; off < 64; off <<= 1) { unsigned t = __shfl_up(incl, off); if (lane >= off) incl += t; }
    if (idx < cnt) L.bbase[idx] = incl - v + running;
    running += __shfl(incl, 63);
  }
  if (lane == 0 && slot >= 0) L.cnts[slot] = (int)running;
}

__global__ __launch_bounds__(BLOCK) void k_scan3(KParams P) {
  Lay L = mklay(P.ws, P.n);
  int tid = threadIdx.x, bid = blockIdx.x;
  int chunk = (P.n + SG - 1)/SG;
  int ig = bid*chunk + tid;
  if (tid < chunk && ig < P.n) {
    int cp = L.colPtr[ig] + (int)L.bbase[bid];
    L.colPtr[ig] = cp; L.cursor[ig] = cp; L.ks1[ig] += 1;
  }
  if (bid == 0 && tid == 0) L.colPtr[P.n] = P.e;
}

__global__ __launch_bounds__(BLOCK) void k_csr(KParams P) {
  Lay L = mklay(P.ws, P.n);
  const int* row = P.ei; const int* col = P.ei + P.e;
  int gid = blockIdx.x*BLOCK + threadIdx.x;
  for (int j = gid; j < P.e; j += NTHE) {
    int pos = atomicAdd(&L.cursor[col[j]], 1);
    L.colSrc[pos] = row[j];
  }
}

__global__ __launch_bounds__(BLOCK) void k_keygen(KParams P) {
  Lay L = mklay(P.ws, P.n);
  int v = blockIdx.x*BLOCK + threadIdx.x;
  if (v >= P.n) return;
  int s = gsum_(L.colSrc, L.ks1, L.colPtr[v], L.colPtr[v+1], L.ks1[v]);
  float upd = L.score[v] / (float)s;
  unsigned u = __float_as_uint(upd);
  u = (u & 0x80000000u) ? (~u) : (u | 0x80000000u);  // ascending map
  L.keyA[v] = ~u;                                    // descending
  L.idxA[v] = (unsigned)v;
}

__global__ __launch_bounds__(BLOCK) void k_sort_local(KParams P, int pass) {
  Lay L = mklay(P.ws, P.n);
  __shared__ int ldsH[1024];
  int tid = threadIdx.x, bid = blockIdx.x, lane = tid & 63, wib = tid >> 6;
  unsigned* sk = (pass & 1) ? L.keyB : L.keyA;
  int shift = pass*8;
  for (int i = tid; i < 1024; i += BLOCK) ldsH[i] = 0;
  __syncthreads();
  int chunk = (P.n + SG - 1)/SG;
  int ig = bid*chunk + tid;
  bool valid = (tid < chunk) && (ig < P.n);
  int dig = 0;
  if (valid) dig = (int)((sk[ig] >> shift) & 255u);
  unsigned long long mmask = __ballot(valid);
  for (int b = 0; b < 8; ++b) {
    unsigned long long bm = __ballot((dig >> b) & 1);
    mmask &= ((dig >> b) & 1) ? bm : ~bm;
  }
  int lp = 0;
  if (valid) {
    lp = __popcll(mmask & ((1ull << lane) - 1ull));
    if (lp == 0) ldsH[wib*256 + dig] = __popcll(mmask);
  }
  __syncthreads();
  if (tid < 256) {
    int c0=ldsH[tid], c1=ldsH[256+tid], c2=ldsH[512+tid], c3=ldsH[768+tid];
    ldsH[tid]=0; ldsH[256+tid]=c0; ldsH[512+tid]=c0+c1; ldsH[768+tid]=c0+c1+c2;
    L.bh[(size_t)tid*SG + bid] = (unsigned)(c0+c1+c2+c3);
  }
  __syncthreads();
  if (valid) L.lrank[ig] = (unsigned)(ldsH[wib*256 + dig] + lp);
}

__global__ __launch_bounds__(BLOCK) void k_sort_scan1(KParams P) {
  Lay L = mklay(P.ws, P.n);
  int g = blockIdx.x*BLOCK + threadIdx.x;
  int dg = g >> 6, lane = g & 63;
  if (dg >= 256) return;
  unsigned running = 0;
  for (int r = 0; r < SG/64; ++r) {
    unsigned v = L.bh[(size_t)dg*SG + r*64 + lane];
    unsigned incl = v;
    for (int off = 1; off < 64; off <<= 1) { unsigned t = __shfl_up(incl, off); if (lane >= off) incl += t; }
    L.bh[(size_t)dg*SG + r*64 + lane] = incl - v + running;
    running += __shfl(incl, 63);
  }
  if (lane == 0) L.dtot[dg] = running;
}

__global__ void k_scanD(KParams P) {   // <<<1,64>>> scan dtot(256) -> dbase
  Lay L = mklay(P.ws, P.n);
  int lane = threadIdx.x;
  unsigned running = 0;
  for (int r = 0; r < 4; ++r) {
    unsigned v = L.dtot[r*64 + lane];
    unsigned incl = v;
    for (int off = 1; off < 64; off <<= 1) { unsigned t = __shfl_up(incl, off); if (lane >= off) incl += t; }
    L.dbase[r*64 + lane] = incl - v + running;
    running += __shfl(incl, 63);
  }
}

__global__ __launch_bounds__(BLOCK) void k_sort_scatter(KParams P, int pass) {
  Lay L = mklay(P.ws, P.n);
  unsigned *sk,*si,*dk,*di;
  if (pass & 1) { sk=L.keyB; si=L.idxB; dk=L.keyA; di=L.idxA; }
  else          { sk=L.keyA; si=L.idxA; dk=L.keyB; di=L.idxB; }
  int tid = threadIdx.x, bid = blockIdx.x;
  int chunk = (P.n + SG - 1)/SG;
  int ig = bid*chunk + tid;
  if (tid < chunk && ig < P.n) {
    unsigned key = sk[ig];
    int dig = (int)((key >> (pass*8)) & 255u);
    unsigned pos = L.dbase[dig] + L.bh[(size_t)dig*SG + bid] + L.lrank[ig];
    dk[pos] = key; di[pos] = si[ig];
  }
}

__global__ __launch_bounds__(BLOCK) void k_rankinit(KParams P) {
  Lay L = mklay(P.ws, P.n);
  int i = blockIdx.x*BLOCK + threadIdx.x;
  if (i >= P.n) return;
  int v = (int)L.idxA[i];
  L.rank[v] = i; L.mr[v] = i; L.mis[v] = 0;
}

__global__ __launch_bounds__(BLOCK, 2) void k_loop(KParams P) {
  cg::grid_group grid = cg::this_grid();
  Lay L = mklay(P.ws, P.n);
  __shared__ int lds[256];
  const int tid = threadIdx.x, bid = blockIdx.x;
  const int gid = bid*BLOCK + tid;
  const int n = P.n;
  const int* __restrict__ cp = L.colPtr;
  const int* __restrict__ cs = L.colSrc;
  int p0 = 0, p1 = 0, myrank = 0;
  if (gid < n) { p0 = cp[gid]; p1 = cp[gid+1]; myrank = L.rank[gid]; }
  int iter = 0;
  for (;;) {
    if (gid < n) L.t1[gid] = gmin_(cs, L.mr, p0, p1, L.mr[gid]);
    grid.sync();
    if (gid < n) {
      int m = gmin_(cs, L.t1, p0, p1, L.t1[gid]);
      L.mr[gid] = m;
      int ms = L.mis[gid] | ((myrank == m) ? 1 : 0);
      L.mis[gid] = ms; L.mm[gid] = ms;
    }
    if (gid == 0) L.cnts[iter & 1] = 0;
    grid.sync();
    if (gid < n) L.t1[gid] = gor_(cs, L.mm, p0, p1, L.mm[gid]);
    grid.sync();
    int localUn = 0;
    if (gid < n) {
      int m = gor_(cs, L.t1, p0, p1, L.t1[gid]);
      if (m) L.mr[gid] = n; else { L.mr[gid] = myrank; localUn = 1; }
    }
    lds[tid] = localUn; __syncthreads();
    for (int off = 128; off > 0; off >>= 1) { if (tid < off) lds[tid] += lds[tid+off]; __syncthreads(); }
    if (tid == 0 && lds[0]) atomicAdd(&L.cnts[iter & 1], lds[0]);
    grid.sync();
    int un = __hip_atomic_load(&L.cnts[iter & 1], __ATOMIC_RELAXED, __HIP_MEMORY_SCOPE_AGENT);
    if (un == 0 || iter >= 500) break;
    ++iter;
  }
  // final khop_min over (mis ? rank : n)
  if (gid < n) L.mm[gid] = L.mis[gid] ? myrank : n;
  grid.sync();
  if (gid < n) L.t1[gid] = gmin_(cs, L.mm, p0, p1, L.mm[gid]);
  grid.sync();
  if (gid < n) L.mr[gid] = gmin_(cs, L.t1, p0, p1, L.t1[gid]);
  // mis prefix scan (block-chunked)
  int chunkL = (n + LGRID - 1)/LGRID;
  int ig = bid*chunkL + tid;
  bool valid = (tid < chunkL) && (ig < n);
  int v2 = valid ? L.mis[ig] : 0;
  lds[tid] = v2; __syncthreads();
  for (int off = 1; off < 256; off <<= 1) {
    int t = (tid >= off) ? lds[tid-off] : 0; __syncthreads();
    lds[tid] += t; __syncthreads();
  }
  if (valid) L.misPre[ig] = lds[tid] - v2;
  if (tid == 0) L.btot[bid] = (unsigned)lds[255];
  grid.sync();
  if (gid < 64) {
    int lane = gid;
    unsigned running = 0;
    for (int r = 0; r*64 < LGRID; ++r) {
      int idx = r*64 + lane;
      unsigned v = (idx < LGRID) ? L.btot[idx] : 0u;
      unsigned incl = v;
      for (int off = 1; off < 64; off <<= 1) { unsigned t = __shfl_up(incl, off); if (lane >= off) incl += t; }
      if (idx < LGRID) L.bbase[idx] = incl - v + running;
      running += __shfl(incl, 63);
    }
    if (lane == 0) L.cnts[2] = (int)running;   // num_mis
  }
  grid.sync();
  if (valid) {
    int p = L.misPre[ig] + (int)L.bbase[bid];
    L.misPre[ig] = p;
    if (L.mis[ig]) L.r2c[L.rank[ig]] = p;
  }
}

__global__ __launch_bounds__(BLOCK) void k_clus(KParams P) {
  Lay L = mklay(P.ws, P.n);
  int gid = blockIdx.x*BLOCK + threadIdx.x;
  int M = L.cnts[2];
  long long M2 = (long long)M*M;
  for (int v = gid; v < P.n; v += NTHE) {
    int r3 = L.mr[v];
    L.clus[v] = (r3 >= 0 && r3 < P.n) ? L.r2c[r3] : 0;
  }
  bool pairOk = (M > 0) && (M2 < 0x7fffffffll) && (L.unionBase + M2 <= P.ws_ints);
  if (pairOk) {
    int m2i = (int)M2;
    for (int i = gid; i < m2i; i += NTHE) L.pairCnt[i] = 0;
  }
}

__global__ __launch_bounds__(BLOCK) void k_pair(KParams P) {
  Lay L = mklay(P.ws, P.n);
  int M = L.cnts[2];
  long long M2 = (long long)M*M;
  bool pairOk = (M > 0) && (M2 < 0x7fffffffll) && (L.unionBase + M2 <= P.ws_ints);
  if (!pairOk) return;
  const int* row = P.ei; const int* col = P.ei + P.e;
  int gid = blockIdx.x*BLOCK + threadIdx.x;
  for (int j = gid; j < P.e; j += NTHE) {
    int a = L.clus[row[j]], b2 = L.clus[col[j]];
    atomicAdd(&L.pairCnt[a*M + b2], 1);
  }
}

__global__ __launch_bounds__(BLOCK) void k_keep1(KParams P) {
  Lay L = mklay(P.ws, P.n);
  __shared__ int lds[256];
  int tid = threadIdx.x, bid = blockIdx.x;
  int M = L.cnts[2];
  long long M2 = (long long)M*M;
  bool pairOk = (M > 0) && (M2 < 0x7fffffffll) && (L.unionBase + M2 <= P.ws_ints);
  int m2i = pairOk ? (int)M2 : 0;
  int chunkP = pairOk ? (m2i + SG - 1)/SG : 0;
  int pstart = bid*chunkP; if (pstart > m2i) pstart = m2i;
  int pend = pstart + chunkP; if (pend > m2i) pend = m2i;
  int localKeep = 0;
  for (int i = pstart + tid; i < pend; i += BLOCK) {
    int c = L.pairCnt[i];
    if (c > 0 && (i / M) != (i % M)) ++localKeep;
  }
  lds[tid] = localKeep; __syncthreads();
  for (int off = 128; off > 0; off >>= 1) { if (tid < off) lds[tid] += lds[tid+off]; __syncthreads(); }
  if (tid == 0) L.btot[bid] = (unsigned)lds[0];
}

__global__ __launch_bounds__(BLOCK) void k_edges(KParams P) {
  Lay L = mklay(P.ws, P.n);
  __shared__ int lds[256];
  int tid = threadIdx.x, bid = blockIdx.x;
  int M = L.cnts[2], EK = L.cnts[3];
  long long M2 = (long long)M*M;
  bool pairOk = (M > 0) && (M2 < 0x7fffffffll) && (L.unionBase + M2 <= P.ws_ints);
  if (!pairOk) return;
  int m2i = (int)M2;
  int chunkP = (m2i + SG - 1)/SG;
  int pstart = bid*chunkP; if (pstart > m2i) pstart = m2i;
  int pend = pstart + chunkP; if (pend > m2i) pend = m2i;
  size_t eBase = (size_t)M * (size_t)P.d;
  bool outOk = (eBase + 3ull*(size_t)EK <= (size_t)P.out_size);
  int running2 = (int)L.bbase[bid];
  for (int t0 = pstart; t0 < pend; t0 += BLOCK) {
    int i = t0 + tid;
    int c = 0, kept = 0, a = 0, b2 = 0;
    if (i < pend) {
      c = L.pairCnt[i];
      a = i / M; b2 = i % M;
      kept = (c > 0 && a != b2) ? 1 : 0;
    }
    lds[tid] = kept; __syncthreads();
    for (int off = 1; off < 256; off <<= 1) {
      int t = (tid >= off) ? lds[tid-off] : 0; __syncthreads();
      lds[tid] += t; __syncthreads();
    }
    int incl = lds[tid], tot = lds[255];
    if (kept && outOk) {
      int j2 = running2 + incl - 1;
      P.out[eBase + (size_t)j2] = (float)a;
      P.out[eBase + (size_t)EK + (size_t)j2] = (float)b2;
      P.out[eBase + 2ull*(size_t)EK + (size_t)j2] = (float)c;
    }
    running2 += tot;
    __syncthreads();
  }
}

__global__ __launch_bounds__(BLOCK) void k_xpool(KParams P) {
  Lay L = mklay(P.ws, P.n);
  int gid = blockIdx.x*BLOCK + threadIdx.x;
  int lane = gid & 63, gwv = gid >> 6;
  int M = L.cnts[2];
  int d4 = P.d >> 2;
  size_t eBase = (size_t)M * (size_t)P.d;
  if (eBase > (size_t)P.out_size) return;
  for (int v = gwv; v < P.n; v += NWVE) {
    if (L.mis[v]) {
      int p = L.misPre[v];
      float sc = L.score[v];
      const float4* xr = (const float4*)(P.x + (size_t)v*P.d);
      float4* outr = (float4*)P.out + (size_t)p*d4;
      for (int q = lane; q < d4; q += 64) {
        float4 xv = xr[q];
        outr[q] = make_float4(xv.x*sc, xv.y*sc, xv.z*sc, xv.w*sc);
      }
    }
  }
}

extern "C" void kernel_launch(void* const* d_in, const int* in_sizes, int n_in,
                              void* d_out, int out_size, void* d_ws, size_t ws_size,
                              hipStream_t stream) {
  KParams P;
  P.x  = (const float*)d_in[0];
  P.ei = (const int*)d_in[1];
  P.w  = (const float*)d_in[2];
  P.bb = (const float*)d_in[3];
  P.out = (float*)d_out;
  P.d = in_sizes[2];            // 256
  P.n = in_sizes[0] / P.d;      // 100000
  P.e = in_sizes[1] / 2;        // 1600000
  P.out_size = out_size;
  P.ws = (int*)d_ws;
  P.ws_ints = (long long)(ws_size / 4);
  const int nblk = (P.n + BLOCK - 1) / BLOCK;

  k_score <<<EGRID, BLOCK, 0, stream>>>(P);
  k_degree<<<EGRID, BLOCK, 0, stream>>>(P);
  k_scan1 <<<SG,    BLOCK, 0, stream>>>(P);
  k_scanB <<<1, 64, 0, stream>>>(P, SG, -1);
  k_scan3 <<<SG,    BLOCK, 0, stream>>>(P);
  k_csr   <<<EGRID, BLOCK, 0, stream>>>(P);
  k_keygen<<<nblk,  BLOCK, 0, stream>>>(P);
  for (int pass = 0; pass < 4; ++pass) {
    k_sort_local  <<<SG, BLOCK, 0, stream>>>(P, pass);
    k_sort_scan1  <<<64, BLOCK, 0, stream>>>(P);
    k_scanD       <<<1, 64,    0, stream>>>(P);
    k_sort_scatter<<<SG, BLOCK, 0, stream>>>(P, pass);
  }
  k_rankinit<<<nblk, BLOCK, 0, stream>>>(P);
  void* args[] = { &P };
  hipLaunchCooperativeKernel((const void*)k_loop, dim3(LGRID), dim3(BLOCK), args, 0, stream);
  k_clus <<<EGRID, BLOCK, 0, stream>>>(P);
  k_pair <<<EGRID, BLOCK, 0, stream>>>(P);
  k_keep1<<<SG,    BLOCK, 0, stream>>>(P);
  k_scanB<<<1, 64, 0, stream>>>(P, SG, 3);
  k_edges<<<SG,    BLOCK, 0, stream>>>(P);
  k_xpool<<<EGRID, BLOCK, 0, stream>>>(P);
}

// Round 4
// 2092.571 us; speedup vs baseline: 3.4105x; 1.1080x over previous
//
#include <hip/hip_runtime.h>
#include <hip/hip_cooperative_groups.h>
#include <math.h>

namespace cg = cooperative_groups;

#define BLOCK 256
#define EGRID 2048                 // edge-parallel / bulk kernels
#define SG    512                  // scan/sort kernels (fixed structure)
#define LGRIDC 128                 // cooperative sparse loop grid
#define NTHE (EGRID*BLOCK)
#define NWVE (NTHE/64)
#define NTHL (LGRIDC*BLOCK)
#define INF_ 0x7fffffff

struct KParams {
  const float* x;
  const int*   ei;
  const float* w;
  const float* bb;
  float* out;
  int n, e, d, out_size;
  int* ws;
  long long ws_ints;
};

struct Lay {
  float* score; int *ks1,*cursor;
  int *keyA,*idxA,*keyB,*idxB,*lrank;      // reused as lists after sort
  int *rank,*mr,*t1,*mis,*mm,*misPre,*r2c,*clus,*colPtr,*rowPtr;
  unsigned *bh,*dtot,*dbase,*btot,*bbase;
  int *cnts,*colSrc,*rowDst,*pairCnt;
  long long unionBase;
};

__device__ __host__ inline Lay mklay(int* ws, int n, int e) {
  Lay L;
  L.score=(float*)ws;
  L.ks1   = ws + (size_t)1*n;
  L.cursor= ws + (size_t)2*n;          // -> mask in loop
  L.keyA  = ws + (size_t)3*n;          // -> active buf A
  L.idxA  = ws + (size_t)4*n;          // -> LA touched list
  L.keyB  = ws + (size_t)5*n;          // -> active buf B
  L.idxB  = ws + (size_t)6*n;
  L.lrank = ws + (size_t)7*n;          // -> LB touched list
  L.rank  = ws + (size_t)8*n;
  L.mr    = ws + (size_t)9*n;          // -> tA ; final khop_min result
  L.t1    = ws + (size_t)10*n;         // -> tB ; fin temp
  L.mis   = ws + (size_t)11*n;
  L.mm    = ws + (size_t)12*n;         // -> fA ; fin temp
  L.misPre= ws + (size_t)13*n;         // dense f1 temp, MA list, post misPre
  L.r2c   = ws + (size_t)14*n;         // outDeg temp, post r2c
  L.clus  = ws + (size_t)15*n;         // row-cursor temp, post clus
  L.colPtr= ws + (size_t)16*n;         // n+1
  L.rowPtr= ws + (size_t)17*n + 64;    // n+1
  int* sm = ws + (size_t)18*n + 128;
  L.bh    = (unsigned*)sm;             // 256*SG
  L.dtot  = L.bh + 256*SG;             // 256
  L.dbase = L.dtot + 256;              // 256
  L.btot  = L.dbase + 256;             // SG
  L.bbase = L.btot + SG;               // SG
  L.cnts  = (int*)(L.bbase + SG);      // 16
  L.unionBase = 18ll*n + 128 + 256ll*SG + 512 + 2ll*SG + 16;
  L.colSrc  = ws + L.unionBase;        // e ints
  L.rowDst  = L.colSrc + e;            // e ints
  L.pairCnt = ws + L.unionBase;        // M*M ints (aliases both, later)
  return L;
}

// ---- unrolled gather reducers ----
__device__ inline int gmin_(const int* __restrict__ s, const int* __restrict__ val,
                            int p, int pe, int m) {
  for (; p+3 < pe; p += 4) {
    int a0=s[p],a1=s[p+1],a2=s[p+2],a3=s[p+3];
    int t0=val[a0],t1=val[a1],t2=val[a2],t3=val[a3];
    t0=min(t0,t1); t2=min(t2,t3); t0=min(t0,t2); if (t0<m) m=t0;
  }
  for (; p<pe; ++p){ int t=val[s[p]]; if (t<m) m=t; }
  return m;
}
__device__ inline int gor_(const int* __restrict__ s, const int* __restrict__ val,
                           int p, int pe, int m) {
  for (; p+3 < pe; p += 4) m |= val[s[p]] | val[s[p+1]] | val[s[p+2]] | val[s[p+3]];
  for (; p<pe; ++p) m |= val[s[p]];
  return m;
}
__device__ inline int gsum_(const int* __restrict__ s, const int* __restrict__ val,
                            int p, int pe, int m) {
  for (; p+3 < pe; p += 4) m += val[s[p]] + val[s[p+1]] + val[s[p+2]] + val[s[p+3]];
  for (; p<pe; ++p) m += val[s[p]];
  return m;
}

// ---------------- phase kernels ----------------
__global__ __launch_bounds__(BLOCK) void k_score(KParams P) {
  Lay L = mklay(P.ws, P.n, P.e);
  int gid = blockIdx.x*BLOCK + threadIdx.x;
  int lane = gid & 63, gwv = gid >> 6;
  int d4 = P.d >> 2;
  double bconst = (double)P.bb[0];
  const float4* w4 = (const float4*)P.w;
  for (int v = gwv; v < P.n; v += NWVE) {
    const float4* xr = (const float4*)(P.x + (size_t)v*P.d);
    double s = 0.0;
    for (int q = lane; q < d4; q += 64) {
      float4 xv = xr[q], wv = w4[q];
      s += (double)xv.x*wv.x + (double)xv.y*wv.y + (double)xv.z*wv.z + (double)xv.w*wv.w;
    }
    for (int off = 32; off > 0; off >>= 1) s += __shfl_down(s, off);
    if (lane == 0) L.score[v] = (float)(1.0/(1.0+exp(-(s+bconst))));
  }
  for (int v = gid; v < P.n; v += NTHE) { L.ks1[v] = 0; L.r2c[v] = 0; }
}

__global__ __launch_bounds__(BLOCK) void k_degree(KParams P) {
  Lay L = mklay(P.ws, P.n, P.e);
  const int* row = P.ei; const int* col = P.ei + P.e;
  int gid = blockIdx.x*BLOCK + threadIdx.x;
  for (int j = gid; j < P.e; j += NTHE) {
    atomicAdd(&L.ks1[col[j]], 1);     // in-degree
    atomicAdd(&L.r2c[row[j]], 1);     // out-degree
  }
}

// chunked exclusive scan over n values src -> dst partials, btot per block
__global__ __launch_bounds__(BLOCK) void k_scan1(KParams P) {
  Lay L = mklay(P.ws, P.n, P.e);
  __shared__ int lds[256];
  int tid = threadIdx.x, bid = blockIdx.x;
  int chunk = (P.n + SG - 1)/SG;
  int ig = bid*chunk + tid;
  bool valid = (tid < chunk) && (ig < P.n);
  int v2 = valid ? L.ks1[ig] : 0;
  lds[tid] = v2; __syncthreads();
  for (int off = 1; off < 256; off <<= 1) {
    int t = (tid >= off) ? lds[tid-off] : 0; __syncthreads();
    lds[tid] += t; __syncthreads();
  }
  if (valid) L.colPtr[ig] = lds[tid] - v2;
  if (tid == 0) L.btot[bid] = (unsigned)lds[255];
}

__global__ void k_scanB(KParams P, int cnt, int slot) {  // <<<1,64>>>
  Lay L = mklay(P.ws, P.n, P.e);
  int lane = threadIdx.x;
  unsigned running = 0;
  for (int r = 0; r*64 < cnt; ++r) {
    int idx = r*64 + lane;
    unsigned v = (idx < cnt) ? L.btot[idx] : 0u;
    unsigned incl = v;
    for (int off = 1; off < 64; off <<= 1) { unsigned t = __shfl_up(incl, off); if (lane >= off) incl += t; }
    if (idx < cnt) L.bbase[idx] = incl - v + running;
    running += __shfl(incl, 63);
  }
  if (lane == 0 && slot >= 0) L.cnts[slot] = (int)running;
}

__global__ __launch_bounds__(BLOCK) void k_scan3(KParams P) {
  Lay L = mklay(P.ws, P.n, P.e);
  int tid = threadIdx.x, bid = blockIdx.x;
  int chunk = (P.n + SG - 1)/SG;
  int ig = bid*chunk + tid;
  if (tid < chunk && ig < P.n) {
    int cp = L.colPtr[ig] + (int)L.bbase[bid];
    L.colPtr[ig] = cp; L.cursor[ig] = cp; L.ks1[ig] += 1;
  }
  if (bid == 0 && tid == 0) L.colPtr[P.n] = P.e;
}

__global__ __launch_bounds__(BLOCK) void k_scanR1(KParams P) {
  Lay L = mklay(P.ws, P.n, P.e);
  __shared__ int lds[256];
  int tid = threadIdx.x, bid = blockIdx.x;
  int chunk = (P.n + SG - 1)/SG;
  int ig = bid*chunk + tid;
  bool valid = (tid < chunk) && (ig < P.n);
  int v2 = valid ? L.r2c[ig] : 0;
  lds[tid] = v2; __syncthreads();
  for (int off = 1; off < 256; off <<= 1) {
    int t = (tid >= off) ? lds[tid-off] : 0; __syncthreads();
    lds[tid] += t; __syncthreads();
  }
  if (valid) L.rowPtr[ig] = lds[tid] - v2;
  if (tid == 0) L.btot[bid] = (unsigned)lds[255];
}

__global__ __launch_bounds__(BLOCK) void k_scanR3(KParams P) {
  Lay L = mklay(P.ws, P.n, P.e);
  int tid = threadIdx.x, bid = blockIdx.x;
  int chunk = (P.n + SG - 1)/SG;
  int ig = bid*chunk + tid;
  if (tid < chunk && ig < P.n) {
    int rp = L.rowPtr[ig] + (int)L.bbase[bid];
    L.rowPtr[ig] = rp; L.clus[ig] = rp;
  }
  if (bid == 0 && tid == 0) L.rowPtr[P.n] = P.e;
}

__global__ __launch_bounds__(BLOCK) void k_csr(KParams P) {
  Lay L = mklay(P.ws, P.n, P.e);
  const int* row = P.ei; const int* col = P.ei + P.e;
  int gid = blockIdx.x*BLOCK + threadIdx.x;
  for (int j = gid; j < P.e; j += NTHE) {
    int r = row[j], c = col[j];
    int pos = atomicAdd(&L.cursor[c], 1);
    L.colSrc[pos] = r;
    int pos2 = atomicAdd(&L.clus[r], 1);
    L.rowDst[pos2] = c;
  }
}

__global__ __launch_bounds__(BLOCK) void k_keygen(KParams P) {
  Lay L = mklay(P.ws, P.n, P.e);
  int v = blockIdx.x*BLOCK + threadIdx.x;
  if (v >= P.n) return;
  int s = gsum_(L.colSrc, L.ks1, L.colPtr[v], L.colPtr[v+1], L.ks1[v]);
  float upd = L.score[v] / (float)s;
  unsigned u = __float_as_uint(upd);
  u = (u & 0x80000000u) ? (~u) : (u | 0x80000000u);  // ascending map
  ((unsigned*)L.keyA)[v] = ~u;                       // descending
  ((unsigned*)L.idxA)[v] = (unsigned)v;
}

__global__ __launch_bounds__(BLOCK) void k_sort_local(KParams P, int pass) {
  Lay L = mklay(P.ws, P.n, P.e);
  __shared__ int ldsH[1024];
  int tid = threadIdx.x, bid = blockIdx.x, lane = tid & 63, wib = tid >> 6;
  unsigned* sk = (pass & 1) ? (unsigned*)L.keyB : (unsigned*)L.keyA;
  int shift = pass*8;
  for (int i = tid; i < 1024; i += BLOCK) ldsH[i] = 0;
  __syncthreads();
  int chunk = (P.n + SG - 1)/SG;
  int ig = bid*chunk + tid;
  bool valid = (tid < chunk) && (ig < P.n);
  int dig = 0;
  if (valid) dig = (int)((sk[ig] >> shift) & 255u);
  unsigned long long mmask = __ballot(valid);
  for (int b = 0; b < 8; ++b) {
    unsigned long long bm = __ballot((dig >> b) & 1);
    mmask &= ((dig >> b) & 1) ? bm : ~bm;
  }
  int lp = 0;
  if (valid) {
    lp = __popcll(mmask & ((1ull << lane) - 1ull));
    if (lp == 0) ldsH[wib*256 + dig] = __popcll(mmask);
  }
  __syncthreads();
  if (tid < 256) {
    int c0=ldsH[tid], c1=ldsH[256+tid], c2=ldsH[512+tid], c3=ldsH[768+tid];
    ldsH[tid]=0; ldsH[256+tid]=c0; ldsH[512+tid]=c0+c1; ldsH[768+tid]=c0+c1+c2;
    L.bh[(size_t)tid*SG + bid] = (unsigned)(c0+c1+c2+c3);
  }
  __syncthreads();
  if (valid) ((unsigned*)L.lrank)[ig] = (unsigned)(ldsH[wib*256 + dig] + lp);
}

__global__ __launch_bounds__(BLOCK) void k_sort_scan1(KParams P) {
  Lay L = mklay(P.ws, P.n, P.e);
  int g = blockIdx.x*BLOCK + threadIdx.x;
  int dg = g >> 6, lane = g & 63;
  if (dg >= 256) return;
  unsigned running = 0;
  for (int r = 0; r < SG/64; ++r) {
    unsigned v = L.bh[(size_t)dg*SG + r*64 + lane];
    unsigned incl = v;
    for (int off = 1; off < 64; off <<= 1) { unsigned t = __shfl_up(incl, off); if (lane >= off) incl += t; }
    L.bh[(size_t)dg*SG + r*64 + lane] = incl - v + running;
    running += __shfl(incl, 63);
  }
  if (lane == 0) L.dtot[dg] = running;
}

__global__ void k_scanD(KParams P) {   // <<<1,64>>>
  Lay L = mklay(P.ws, P.n, P.e);
  int lane = threadIdx.x;
  unsigned running = 0;
  for (int r = 0; r < 4; ++r) {
    unsigned v = L.dtot[r*64 + lane];
    unsigned incl = v;
    for (int off = 1; off < 64; off <<= 1) { unsigned t = __shfl_up(incl, off); if (lane >= off) incl += t; }
    L.dbase[r*64 + lane] = incl - v + running;
    running += __shfl(incl, 63);
  }
}

__global__ __launch_bounds__(BLOCK) void k_sort_scatter(KParams P, int pass) {
  Lay L = mklay(P.ws, P.n, P.e);
  unsigned *sk,*si,*dk,*di;
  if (pass & 1) { sk=(unsigned*)L.keyB; si=(unsigned*)L.idxB; dk=(unsigned*)L.keyA; di=(unsigned*)L.idxA; }
  else          { sk=(unsigned*)L.keyA; si=(unsigned*)L.idxA; dk=(unsigned*)L.keyB; di=(unsigned*)L.idxB; }
  int tid = threadIdx.x, bid = blockIdx.x;
  int chunk = (P.n + SG - 1)/SG;
  int ig = bid*chunk + tid;
  if (tid < chunk && ig < P.n) {
    unsigned key = sk[ig];
    int dig = (int)((key >> (pass*8)) & 255u);
    unsigned pos = L.dbase[dig] + L.bh[(size_t)dig*SG + bid] + ((unsigned*)L.lrank)[ig];
    dk[pos] = key; di[pos] = si[ig];
  }
}

__global__ __launch_bounds__(BLOCK) void k_rankinit(KParams P) {
  Lay L = mklay(P.ws, P.n, P.e);
  int i = blockIdx.x*BLOCK + threadIdx.x;
  if (blockIdx.x == 0 && threadIdx.x < 12) L.cnts[4 + threadIdx.x] = 0;
  if (i >= P.n) return;
  int v = (int)((unsigned*)L.idxA)[i];
  L.rank[v] = i; L.mis[v] = 0;
}

// ---- dense iteration 0 (gather over in-CSR) ----
__global__ __launch_bounds__(BLOCK) void k_d1(KParams P) {
  Lay L = mklay(P.ws, P.n, P.e);
  int v = blockIdx.x*BLOCK + threadIdx.x;
  if (v >= P.n) return;
  L.mr[v] = gmin_(L.colSrc, L.rank, L.colPtr[v], L.colPtr[v+1], L.rank[v]);
}
__global__ __launch_bounds__(BLOCK) void k_d2(KParams P) {
  Lay L = mklay(P.ws, P.n, P.e);
  int v = blockIdx.x*BLOCK + threadIdx.x;
  if (v >= P.n) return;
  int m = gmin_(L.colSrc, L.mr, L.colPtr[v], L.colPtr[v+1], L.mr[v]);
  L.mis[v] = (L.rank[v] == m) ? 1 : 0;
}
__global__ __launch_bounds__(BLOCK) void k_d3(KParams P) {
  Lay L = mklay(P.ws, P.n, P.e);
  int v = blockIdx.x*BLOCK + threadIdx.x;
  if (v >= P.n) return;
  L.misPre[v] = gor_(L.colSrc, L.mis, L.colPtr[v], L.colPtr[v+1], L.mis[v]);
}
__global__ __launch_bounds__(BLOCK) void k_d4(KParams P) {
  Lay L = mklay(P.ws, P.n, P.e);
  int v = blockIdx.x*BLOCK + threadIdx.x;
  if (v >= P.n) return;
  int msk = gor_(L.colSrc, L.misPre, L.colPtr[v], L.colPtr[v+1], L.misPre[v]);
  L.cursor[v] = msk;           // mask
  L.mr[v] = INF_;              // tA
  L.t1[v] = INF_;              // tB
  L.mm[v] = 0;                 // fA
  if (!msk) { int k = atomicAdd(&L.cnts[4], 1); L.keyA[k] = v; }
}

// ---- cooperative sparse loop ----
__global__ __launch_bounds__(BLOCK) void k_loop(KParams P) {
  cg::grid_group grid = cg::this_grid();
  Lay L = mklay(P.ws, P.n, P.e);
  const int gid = blockIdx.x*BLOCK + threadIdx.x;
  const int* __restrict__ rp = L.rowPtr;
  const int* __restrict__ rd = L.rowDst;
  int* tA = L.mr; int* tB = L.t1; int* fA = L.mm; int* mask = L.cursor;
  int* LA = L.idxA; int* LB = L.lrank; int* MA = L.misPre;
  int* cn = L.cnts;
  int iter = 0;
  for (;;) {
    const int q = iter & 1;
    int* act  = q ? L.keyB : L.keyA;
    int* nact = q ? L.keyA : L.keyB;
    const int A = __hip_atomic_load(&cn[4+q], __ATOMIC_RELAXED, __HIP_MEMORY_SCOPE_AGENT);
    // S1: hop-1 min scatter from active (self + out-edges), first-touch list LA
    for (int i = gid; i < A; i += NTHL) {
      int w = act[i]; int r = L.rank[w];
      if (atomicMin(&tA[w], r) == INF_) { int k = atomicAdd(&cn[8+4*q], 1); LA[k] = w; }
      int p1 = rp[w+1];
      for (int p = rp[w]; p < p1; ++p) {
        int c = rd[p];
        if (atomicMin(&tA[c], r) == INF_) { int k = atomicAdd(&cn[8+4*q], 1); LA[k] = c; }
      }
    }
    grid.sync();
    // S2: hop-2 min scatter from LA
    const int nLA = __hip_atomic_load(&cn[8+4*q], __ATOMIC_RELAXED, __HIP_MEMORY_SCOPE_AGENT);
    for (int i = gid; i < nLA; i += NTHL) {
      int u = LA[i]; int v1 = tA[u];
      if (atomicMin(&tB[u], v1) == INF_) { int k = atomicAdd(&cn[9+4*q], 1); LB[k] = u; }
      int p1 = rp[u+1];
      for (int p = rp[u]; p < p1; ++p) {
        int c = rd[p];
        if (atomicMin(&tB[c], v1) == INF_) { int k = atomicAdd(&cn[9+4*q], 1); LB[k] = c; }
      }
    }
    grid.sync();
    // S3: MIS detect + mask hop-1 scatter; zero next-parity counters
    if (gid == 0) {
      int nq = 1 - q;
      cn[4+nq] = 0; cn[8+4*nq] = 0; cn[9+4*nq] = 0; cn[10+4*nq] = 0; cn[11+4*nq] = 0;
    }
    for (int i = gid; i < A; i += NTHL) {
      int w = act[i];
      if (L.rank[w] == tB[w]) {
        L.mis[w] = 1;
        if (atomicMax(&fA[w], 1) == 0) { int k = atomicAdd(&cn[10+4*q], 1); MA[k] = w; }
        int p1 = rp[w+1];
        for (int p = rp[w]; p < p1; ++p) {
          int c = rd[p];
          if (atomicMax(&fA[c], 1) == 0) { int k = atomicAdd(&cn[10+4*q], 1); MA[k] = c; }
        }
      }
    }
    grid.sync();
    // S4: mask hop-2 from MA
    const int nMA = __hip_atomic_load(&cn[10+4*q], __ATOMIC_RELAXED, __HIP_MEMORY_SCOPE_AGENT);
    for (int i = gid; i < nMA; i += NTHL) {
      int u = MA[i];
      mask[u] = 1;
      int p1 = rp[u+1];
      for (int p = rp[u]; p < p1; ++p) mask[rd[p]] = 1;
    }
    grid.sync();
    // S5: rebuild active; reset touched state
    const int nLB = __hip_atomic_load(&cn[9+4*q], __ATOMIC_RELAXED, __HIP_MEMORY_SCOPE_AGENT);
    for (int i = gid; i < A; i += NTHL) {
      int w = act[i];
      if (!mask[w]) { int k = atomicAdd(&cn[4+(1-q)], 1); nact[k] = w; }
    }
    for (int i = gid; i < nLA; i += NTHL) tA[LA[i]] = INF_;
    for (int i = gid; i < nLB; i += NTHL) tB[LB[i]] = INF_;
    for (int i = gid; i < nMA; i += NTHL) fA[MA[i]] = 0;
    grid.sync();
    int nA = __hip_atomic_load(&cn[4+(1-q)], __ATOMIC_RELAXED, __HIP_MEMORY_SCOPE_AGENT);
    if (nA == 0 || iter >= 300) break;
    ++iter;
  }
}

// ---- final khop_min over (mis ? rank : n) ----
__global__ __launch_bounds__(BLOCK) void k_fin0(KParams P) {
  Lay L = mklay(P.ws, P.n, P.e);
  int v = blockIdx.x*BLOCK + threadIdx.x;
  if (v >= P.n) return;
  L.mm[v] = L.mis[v] ? L.rank[v] : P.n;
}
__global__ __launch_bounds__(BLOCK) void k_fin1(KParams P) {
  Lay L = mklay(P.ws, P.n, P.e);
  int v = blockIdx.x*BLOCK + threadIdx.x;
  if (v >= P.n) return;
  L.t1[v] = gmin_(L.colSrc, L.mm, L.colPtr[v], L.colPtr[v+1], L.mm[v]);
}
__global__ __launch_bounds__(BLOCK) void k_fin2(KParams P) {
  Lay L = mklay(P.ws, P.n, P.e);
  int v = blockIdx.x*BLOCK + threadIdx.x;
  if (v >= P.n) return;
  L.mr[v] = gmin_(L.colSrc, L.t1, L.colPtr[v], L.colPtr[v+1], L.t1[v]);
}

// ---- mis prefix scan -> misPre, num_mis, r2c ----
__global__ __launch_bounds__(BLOCK) void k_scanM1(KParams P) {
  Lay L = mklay(P.ws, P.n, P.e);
  __shared__ int lds[256];
  int tid = threadIdx.x, bid = blockIdx.x;
  int chunk = (P.n + SG - 1)/SG;
  int ig = bid*chunk + tid;
  bool valid = (tid < chunk) && (ig < P.n);
  int v2 = valid ? L.mis[ig] : 0;
  lds[tid] = v2; __syncthreads();
  for (int off = 1; off < 256; off <<= 1) {
    int t = (tid >= off) ? lds[tid-off] : 0; __syncthreads();
    lds[tid] += t; __syncthreads();
  }
  if (valid) L.misPre[ig] = lds[tid] - v2;
  if (tid == 0) L.btot[bid] = (unsigned)lds[255];
}
__global__ __launch_bounds__(BLOCK) void k_scanM3(KParams P) {
  Lay L = mklay(P.ws, P.n, P.e);
  int tid = threadIdx.x, bid = blockIdx.x;
  int chunk = (P.n + SG - 1)/SG;
  int ig = bid*chunk + tid;
  if (tid < chunk && ig < P.n) {
    int p = L.misPre[ig] + (int)L.bbase[bid];
    L.misPre[ig] = p;
    if (L.mis[ig]) L.r2c[L.rank[ig]] = p;
  }
}

__global__ __launch_bounds__(BLOCK) void k_clus(KParams P) {
  Lay L = mklay(P.ws, P.n, P.e);
  int gid = blockIdx.x*BLOCK + threadIdx.x;
  int M = L.cnts[2];
  long long M2 = (long long)M*M;
  for (int v = gid; v < P.n; v += NTHE) {
    int r3 = L.mr[v];
    L.clus[v] = (r3 >= 0 && r3 < P.n) ? L.r2c[r3] : 0;
  }
  bool pairOk = (M > 0) && (M2 < 0x7fffffffll) && (L.unionBase + M2 <= P.ws_ints);
  if (pairOk) {
    int m2i = (int)M2;
    for (int i = gid; i < m2i; i += NTHE) L.pairCnt[i] = 0;
  }
}

__global__ __launch_bounds__(BLOCK) void k_pair(KParams P) {
  Lay L = mklay(P.ws, P.n, P.e);
  int M = L.cnts[2];
  long long M2 = (long long)M*M;
  bool pairOk = (M > 0) && (M2 < 0x7fffffffll) && (L.unionBase + M2 <= P.ws_ints);
  if (!pairOk) return;
  const int* row = P.ei; const int* col = P.ei + P.e;
  int gid = blockIdx.x*BLOCK + threadIdx.x;
  for (int j = gid; j < P.e; j += NTHE) {
    int a = L.clus[row[j]], b2 = L.clus[col[j]];
    atomicAdd(&L.pairCnt[a*M + b2], 1);
  }
}

__global__ __launch_bounds__(BLOCK) void k_keep1(KParams P) {
  Lay L = mklay(P.ws, P.n, P.e);
  __shared__ int lds[256];
  int tid = threadIdx.x, bid = blockIdx.x;
  int M = L.cnts[2];
  long long M2 = (long long)M*M;
  bool pairOk = (M > 0) && (M2 < 0x7fffffffll) && (L.unionBase + M2 <= P.ws_ints);
  int m2i = pairOk ? (int)M2 : 0;
  int chunkP = pairOk ? (m2i + SG - 1)/SG : 0;
  int pstart = bid*chunkP; if (pstart > m2i) pstart = m2i;
  int pend = pstart + chunkP; if (pend > m2i) pend = m2i;
  int localKeep = 0;
  for (int i = pstart + tid; i < pend; i += BLOCK) {
    int c = L.pairCnt[i];
    if (c > 0 && (i / M) != (i % M)) ++localKeep;
  }
  lds[tid] = localKeep; __syncthreads();
  for (int off = 128; off > 0; off >>= 1) { if (tid < off) lds[tid] += lds[tid+off]; __syncthreads(); }
  if (tid == 0) L.btot[bid] = (unsigned)lds[0];
}

__global__ __launch_bounds__(BLOCK) void k_edges(KParams P) {
  Lay L = mklay(P.ws, P.n, P.e);
  __shared__ int lds[256];
  int tid = threadIdx.x, bid = blockIdx.x;
  int M = L.cnts[2], EK = L.cnts[3];
  long long M2 = (long long)M*M;
  bool pairOk = (M > 0) && (M2 < 0x7fffffffll) && (L.unionBase + M2 <= P.ws_ints);
  if (!pairOk) return;
  int m2i = (int)M2;
  int chunkP = (m2i + SG - 1)/SG;
  int pstart = bid*chunkP; if (pstart > m2i) pstart = m2i;
  int pend = pstart + chunkP; if (pend > m2i) pend = m2i;
  size_t eBase = (size_t)M * (size_t)P.d;
  bool outOk = (eBase + 3ull*(size_t)EK <= (size_t)P.out_size);
  int running2 = (int)L.bbase[bid];
  for (int t0 = pstart; t0 < pend; t0 += BLOCK) {
    int i = t0 + tid;
    int c = 0, kept = 0, a = 0, b2 = 0;
    if (i < pend) {
      c = L.pairCnt[i];
      a = i / M; b2 = i % M;
      kept = (c > 0 && a != b2) ? 1 : 0;
    }
    lds[tid] = kept; __syncthreads();
    for (int off = 1; off < 256; off <<= 1) {
      int t = (tid >= off) ? lds[tid-off] : 0; __syncthreads();
      lds[tid] += t; __syncthreads();
    }
    int incl = lds[tid], tot = lds[255];
    if (kept && outOk) {
      int j2 = running2 + incl - 1;
      P.out[eBase + (size_t)j2] = (float)a;
      P.out[eBase + (size_t)EK + (size_t)j2] = (float)b2;
      P.out[eBase + 2ull*(size_t)EK + (size_t)j2] = (float)c;
    }
    running2 += tot;
    __syncthreads();
  }
}

__global__ __launch_bounds__(BLOCK) void k_xpool(KParams P) {
  Lay L = mklay(P.ws, P.n, P.e);
  int gid = blockIdx.x*BLOCK + threadIdx.x;
  int lane = gid & 63, gwv = gid >> 6;
  int M = L.cnts[2];
  int d4 = P.d >> 2;
  size_t eBase = (size_t)M * (size_t)P.d;
  if (eBase > (size_t)P.out_size) return;
  for (int v = gwv; v < P.n; v += NWVE) {
    if (L.mis[v]) {
      int p = L.misPre[v];
      float sc = L.score[v];
      const float4* xr = (const float4*)(P.x + (size_t)v*P.d);
      float4* outr = (float4*)P.out + (size_t)p*d4;
      for (int q = lane; q < d4; q += 64) {
        float4 xv = xr[q];
        outr[q] = make_float4(xv.x*sc, xv.y*sc, xv.z*sc, xv.w*sc);
      }
    }
  }
}

extern "C" void kernel_launch(void* const* d_in, const int* in_sizes, int n_in,
                              void* d_out, int out_size, void* d_ws, size_t ws_size,
                              hipStream_t stream) {
  KParams P;
  P.x  = (const float*)d_in[0];
  P.ei = (const int*)d_in[1];
  P.w  = (const float*)d_in[2];
  P.bb = (const float*)d_in[3];
  P.out = (float*)d_out;
  P.d = in_sizes[2];            // 256
  P.n = in_sizes[0] / P.d;      // 100000
  P.e = in_sizes[1] / 2;        // 1600000
  P.out_size = out_size;
  P.ws = (int*)d_ws;
  P.ws_ints = (long long)(ws_size / 4);
  const int nblk = (P.n + BLOCK - 1) / BLOCK;

  k_score <<<EGRID, BLOCK, 0, stream>>>(P);
  k_degree<<<EGRID, BLOCK, 0, stream>>>(P);
  k_scan1 <<<SG,    BLOCK, 0, stream>>>(P);
  k_scanB <<<1, 64, 0, stream>>>(P, SG, -1);
  k_scan3 <<<SG,    BLOCK, 0, stream>>>(P);
  k_scanR1<<<SG,    BLOCK, 0, stream>>>(P);
  k_scanB <<<1, 64, 0, stream>>>(P, SG, -1);
  k_scanR3<<<SG,    BLOCK, 0, stream>>>(P);
  k_csr   <<<EGRID, BLOCK, 0, stream>>>(P);
  k_keygen<<<nblk,  BLOCK, 0, stream>>>(P);
  for (int pass = 0; pass < 4; ++pass) {
    k_sort_local  <<<SG, BLOCK, 0, stream>>>(P, pass);
    k_sort_scan1  <<<64, BLOCK, 0, stream>>>(P);
    k_scanD       <<<1, 64,    0, stream>>>(P);
    k_sort_scatter<<<SG, BLOCK, 0, stream>>>(P, pass);
  }
  k_rankinit<<<nblk, BLOCK, 0, stream>>>(P);
  k_d1<<<nblk, BLOCK, 0, stream>>>(P);
  k_d2<<<nblk, BLOCK, 0, stream>>>(P);
  k_d3<<<nblk, BLOCK, 0, stream>>>(P);
  k_d4<<<nblk, BLOCK, 0, stream>>>(P);
  void* args[] = { &P };
  hipLaunchCooperativeKernel((const void*)k_loop, dim3(LGRIDC), dim3(BLOCK), args, 0, stream);
  k_fin0<<<nblk, BLOCK, 0, stream>>>(P);
  k_fin1<<<nblk, BLOCK, 0, stream>>>(P);
  k_fin2<<<nblk, BLOCK, 0, stream>>>(P);
  k_scanM1<<<SG, BLOCK, 0, stream>>>(P);
  k_scanB <<<1, 64, 0, stream>>>(P, SG, 2);
  k_scanM3<<<SG, BLOCK, 0, stream>>>(P);
  k_clus <<<EGRID, BLOCK, 0, stream>>>(P);
  k_pair <<<EGRID, BLOCK, 0, stream>>>(P);
  k_keep1<<<SG,    BLOCK, 0, stream>>>(P);
  k_scanB<<<1, 64, 0, stream>>>(P, SG, 3);
  k_edges<<<SG,    BLOCK, 0, stream>>>(P);
  k_xpool<<<EGRID, BLOCK, 0, stream>>>(P);
}